// Round 2
// baseline (152.082 us; speedup 1.0000x reference)
//
#include <hip/hip_runtime.h>
#include <hip/hip_bf16.h>
#include <stdint.h>

#define N 8192
#define D 512
#define TILE 128
#define NTB (N / TILE)                // 64 tile-rows (= #slices)
#define NBLK (NTB * (NTB + 1) / 2)    // 2080 upper-tri blocks
#define PANEL_BYTES (TILE * D)        // 65536 B per 128-row fp8 panel

typedef long long i64;
typedef __attribute__((ext_vector_type(4))) float f32x4;
typedef __attribute__((ext_vector_type(8))) int i32x8;

// Fn2 swizzled fp8 layout (R7, verified):
//   byte(p, kc, ks, q, lr) = p*65536 + kc*8192 + ks*4096 + q*1024 + lr*8
// values = fp8_e4m3(16 * normalized_row)
__global__ void cc_normalize(const float* __restrict__ F, uint8_t* __restrict__ Fn2,
                             float* __restrict__ out) {
    if (blockIdx.x == 0 && threadIdx.x == 0) out[0] = 0.0f;
    const int row  = blockIdx.x * 4 + (threadIdx.x >> 6);
    const int lane = threadIdx.x & 63;
    const float* p = F + (size_t)row * D + lane * 8;
    float4 a = *(const float4*)p;
    float4 b = *(const float4*)(p + 4);
    float ss = a.x*a.x + a.y*a.y + a.z*a.z + a.w*a.w
             + b.x*b.x + b.y*b.y + b.z*b.z + b.w*b.w;
    #pragma unroll
    for (int m = 32; m; m >>= 1) ss += __shfl_xor(ss, m, 64);
    const float inv = 16.0f / fmaxf(sqrtf(ss), 1e-12f);
    int lo = 0, hi = 0;
    lo = __builtin_amdgcn_cvt_pk_fp8_f32(a.x*inv, a.y*inv, lo, false);
    lo = __builtin_amdgcn_cvt_pk_fp8_f32(a.z*inv, a.w*inv, lo, true);
    hi = __builtin_amdgcn_cvt_pk_fp8_f32(b.x*inv, b.y*inv, hi, false);
    hi = __builtin_amdgcn_cvt_pk_fp8_f32(b.z*inv, b.w*inv, hi, true);
    const size_t idx = (size_t)(row >> 7) * PANEL_BYTES + (size_t)lane * 1024 + (row & 127) * 8;
    *(int2*)(Fn2 + idx) = make_int2(lo, hi);
}

// R15: same structure as R14 (MX-scaled 16x16x128 fp8 MFMA, no LDS staging,
// Fn2 is L2-resident) but the operand fragments are built with constant-index
// vector inserts from int2 loads — R14's union-based type-pun defeated SROA
// and put a[]/b[] in scratch (VGPR=84, ~210 MB phantom HBM traffic, MfmaUtil 8%).
__device__ __forceinline__ i32x8 load_frag(const uint8_t* p) {
    const int2 w0 = *(const int2*)(p);
    const int2 w1 = *(const int2*)(p + 1024);
    const int2 w2 = *(const int2*)(p + 2048);
    const int2 w3 = *(const int2*)(p + 3072);
    i32x8 v;
    v[0] = w0.x; v[1] = w0.y;
    v[2] = w1.x; v[3] = w1.y;
    v[4] = w2.x; v[5] = w2.y;
    v[6] = w3.x; v[7] = w3.y;
    return v;
}

__global__ __launch_bounds__(256, 3)
void cc_gemm(const uint8_t* __restrict__ Fn2, const int* __restrict__ cl,
             float* __restrict__ Pt, float* __restrict__ Pp) {
    __shared__ int crow[TILE], ccol[TILE];
    __shared__ float2 rsum[2][TILE];
    __shared__ float2 csum[2][TILE];

    const int tid  = threadIdx.x;
    const int wave = tid >> 6;
    const int lane = tid & 63;

    int rem = blockIdx.x, bm = 0;
    while (rem >= NTB - bm) { rem -= NTB - bm; ++bm; }
    const int bn = bm + rem;
    const bool diag = (bm == bn);

    if (tid < TILE)            crow[tid]        = cl[bm * TILE + tid];
    else                       ccol[tid - TILE] = cl[bn * TILE + (tid - TILE)];

    const int wr = wave >> 1, wc = wave & 1;    // 2x2 wave grid, 64x64 each
    const int q   = lane >> 4;
    const int n15 = lane & 15;

    f32x4 acc[4][4];
    #pragma unroll
    for (int t = 0; t < 4; ++t)
        #pragma unroll
        for (int u = 0; u < 4; ++u) acc[t][u] = (f32x4)(0.0f);

    // K=128 operand: lane (q,n15) holds row/col n15, k = q*32 + reg*4 + byte.
    // In Fn2 layout: kc = 2c+(q>>1), ks = q&1, sub-block p at stride 1024:
    // 4 int2 loads from this per-lane base (load_frag).
    const int koff = (q >> 1) * 8192 + (q & 1) * 4096 + n15 * 8;
    const uint8_t* Ag = Fn2 + (size_t)bm * PANEL_BYTES + koff + (wr * 64) * 8;
    const uint8_t* Bg = Fn2 + (size_t)bn * PANEL_BYTES + koff + (wc * 64) * 8;

    #pragma unroll
    for (int c = 0; c < D / 128; ++c) {
        i32x8 a[4], b[4];
        #pragma unroll
        for (int t = 0; t < 4; ++t) a[t] = load_frag(Ag + c * 16384 + t * 128);
        #pragma unroll
        for (int u = 0; u < 4; ++u) b[u] = load_frag(Bg + c * 16384 + u * 128);
        #pragma unroll
        for (int t = 0; t < 4; ++t)
            #pragma unroll
            for (int u = 0; u < 4; ++u)
                acc[t][u] = __builtin_amdgcn_mfma_scale_f32_16x16x128_f8f6f4(
                    a[t], b[u], acc[t][u],
                    0, 0,                 // cbsz=fp8(e4m3), blgp=fp8(e4m3)
                    0, 0x7F7F7F7Fu,       // A scale: any byte = 127 -> 2^0
                    0, 0x7F7F7F7Fu);      // B scale: unit
    }

    __syncthreads();   // crow/ccol visible to all waves for the epilogue

    // epilogue: sim = dot/256; e = exp2(dot * 10*log2(e)/256)
    // C layout col=lane&15, row=q*4+reg (shape-determined, same as 16x16x32)
    const float SC = 0.05635527503472514f;
    int cc[4];
    #pragma unroll
    for (int u = 0; u < 4; ++u) cc[u] = ccol[wc * 64 + u * 16 + n15];

    float ra[16], rp[16];            // per-lane row partials, idx = t*4+r
    float ce[4] = {0.f, 0.f, 0.f, 0.f};
    float cp2[4] = {0.f, 0.f, 0.f, 0.f};

    #pragma unroll
    for (int t = 0; t < 4; ++t) {
        #pragma unroll
        for (int r = 0; r < 4; ++r) {
            const int myc = crow[wr * 64 + t * 16 + q * 4 + r];
            float te = 0.0f, tp = 0.0f;
            #pragma unroll
            for (int u = 0; u < 4; ++u) {
                const float e  = exp2f(acc[t][u][r] * SC);
                const float ep = (cc[u] == myc) ? e : 0.0f;
                te += e;  tp += ep;
                ce[u] += e;  cp2[u] += ep;
            }
            ra[t * 4 + r] = te;  rp[t * 4 + r] = tp;
        }
    }

    // tree-packed reduction (R13-verified): 16 row sums over 16 lanes,
    // 15 shuffles/array. After stage m the kept index gains `half` iff lane&m.
    {
        int len = 16;
        #pragma unroll
        for (int m = 1; m <= 8; m <<= 1) {
            const int half = len >> 1;
            const bool hiL = (lane & m) != 0;
            #pragma unroll
            for (int j = 0; j < half; ++j) {
                float sa = hiL ? ra[j] : ra[j + half];
                float sp = hiL ? rp[j] : rp[j + half];
                sa = __shfl_xor(sa, m, 64);
                sp = __shfl_xor(sp, m, 64);
                ra[j] = (hiL ? ra[j + half] : ra[j]) + sa;
                rp[j] = (hiL ? rp[j + half] : rp[j]) + sp;
            }
            len = half;
        }
        const int idx = ((n15 & 1) << 3) | ((n15 & 2) << 1) | ((n15 & 4) >> 1) | ((n15 & 8) >> 3);
        const int row = wr * 64 + (idx >> 2) * 16 + q * 4 + (idx & 3);
        rsum[wc][row] = make_float2(ra[0], rp[0]);
    }

    // column sums: 4 values over the 4 q-groups (masks 16, 32), 3 shuffles/array
    if (!diag) {
        int len = 4;
        #pragma unroll
        for (int m = 16; m <= 32; m <<= 1) {
            const int half = len >> 1;
            const bool hiL = (lane & m) != 0;
            #pragma unroll
            for (int j = 0; j < half; ++j) {
                float se = hiL ? ce[j] : ce[j + half];
                float sp = hiL ? cp2[j] : cp2[j + half];
                se = __shfl_xor(se, m, 64);
                sp = __shfl_xor(sp, m, 64);
                ce[j] = (hiL ? ce[j + half] : ce[j]) + se;
                cp2[j] = (hiL ? cp2[j + half] : cp2[j]) + sp;
            }
            len = half;
        }
        const int u = (((lane >> 4) & 1) << 1) | ((lane >> 5) & 1);
        const int col = wc * 64 + u * 16 + n15;
        csum[wr][col] = make_float2(ce[0], cp2[0]);
    }

    __syncthreads();
    if (tid < TILE) {
        const float2 r0 = rsum[0][tid], r1 = rsum[1][tid];
        const size_t o = (size_t)bn * N + bm * TILE + tid;
        Pt[o] = r0.x + r1.x;  Pp[o] = r0.y + r1.y;
    } else if (!diag) {
        const int c = tid - TILE;
        const float2 c0 = csum[0][c], c1 = csum[1][c];
        const size_t o = (size_t)bm * N + bn * TILE + c;
        Pt[o] = c0.x + c1.x;  Pp[o] = c0.y + c1.y;
    }
}

// 32 blocks x 256: row i sums its 64 slices, loss, block-reduce, atomicAdd out
__global__ void cc_finalize(const float* __restrict__ Pt, const float* __restrict__ Pp,
                            float* __restrict__ out) {
    __shared__ float red[4];
    const int i = blockIdx.x * 256 + threadIdx.x;
    float tv = 0.0f, pv = 0.0f;
    #pragma unroll 8
    for (int s = 0; s < NTB; ++s) {
        tv += Pt[(size_t)s * N + i];
        pv += Pp[(size_t)s * N + i];
    }
    float l = __logf(tv + 1e-8f) - __logf(pv);
    #pragma unroll
    for (int m = 32; m; m >>= 1) l += __shfl_xor(l, m, 64);
    const int wv = threadIdx.x >> 6, lane = threadIdx.x & 63;
    if (lane == 0) red[wv] = l;
    __syncthreads();
    if (threadIdx.x == 0) atomicAdd(out, red[0] + red[1] + red[2] + red[3]);
}

extern "C" void kernel_launch(void* const* d_in, const int* in_sizes, int n_in,
                              void* d_out, int out_size, void* d_ws, size_t ws_size,
                              hipStream_t stream) {
    const float* F  = (const float*)d_in[0];
    const int*   cl = (const int*)d_in[1];
    float* out = (float*)d_out;

    uint8_t* Fn2 = (uint8_t*)d_ws;                               // 4 MB fp8 swizzled
    float* Pt  = (float*)((char*)d_ws + (size_t)N * D);          // 2 MB
    float* Pp  = Pt + (size_t)NTB * N;                           // 2 MB

    cc_normalize<<<N / 4, 256, 0, stream>>>(F, Fn2, out);
    cc_gemm<<<NBLK, 256, 0, stream>>>(Fn2, cl, Pt, Pp);
    cc_finalize<<<N / 256, 256, 0, stream>>>(Pt, Pp, out);
}

// Round 3
// 116.928 us; speedup vs baseline: 1.3006x; 1.3006x over previous
//
#include <hip/hip_runtime.h>
#include <hip/hip_bf16.h>
#include <stdint.h>

#define N 8192
#define D 512
#define TILE 128
#define NTB (N / TILE)                // 64 tile-rows (= #slices)
#define NBLK (NTB * (NTB + 1) / 2)    // 2080 upper-tri blocks
#define PANEL_BYTES (TILE * D)        // 65536 B per 128-row fp8 panel

typedef long long i64;
typedef __attribute__((ext_vector_type(4))) float f32x4;
typedef __attribute__((ext_vector_type(8))) int i32x8;

// Fn2 swizzled fp8 layout (R7, verified):
//   byte(p, kc, ks, q, lr) = p*65536 + kc*8192 + ks*4096 + q*1024 + lr*8
// values = fp8_e4m3(16 * normalized_row)
__global__ void cc_normalize(const float* __restrict__ F, uint8_t* __restrict__ Fn2,
                             float* __restrict__ out) {
    if (blockIdx.x == 0 && threadIdx.x == 0) out[0] = 0.0f;
    const int row  = blockIdx.x * 4 + (threadIdx.x >> 6);
    const int lane = threadIdx.x & 63;
    const float* p = F + (size_t)row * D + lane * 8;
    float4 a = *(const float4*)p;
    float4 b = *(const float4*)(p + 4);
    float ss = a.x*a.x + a.y*a.y + a.z*a.z + a.w*a.w
             + b.x*b.x + b.y*b.y + b.z*b.z + b.w*b.w;
    #pragma unroll
    for (int m = 32; m; m >>= 1) ss += __shfl_xor(ss, m, 64);
    const float inv = 16.0f / fmaxf(sqrtf(ss), 1e-12f);
    int lo = 0, hi = 0;
    lo = __builtin_amdgcn_cvt_pk_fp8_f32(a.x*inv, a.y*inv, lo, false);
    lo = __builtin_amdgcn_cvt_pk_fp8_f32(a.z*inv, a.w*inv, lo, true);
    hi = __builtin_amdgcn_cvt_pk_fp8_f32(b.x*inv, b.y*inv, hi, false);
    hi = __builtin_amdgcn_cvt_pk_fp8_f32(b.z*inv, b.w*inv, hi, true);
    const size_t idx = (size_t)(row >> 7) * PANEL_BYTES + (size_t)lane * 1024 + (row & 127) * 8;
    *(int2*)(Fn2 + idx) = make_int2(lo, hi);
}

// R16: MX-scaled 16x16x128 fp8 MFMA, no LDS staging (Fn2 L2-resident).
// R14/R15 post-mortem: i32x8 OPERAND ARRAYS alloca'd to scratch (VGPR=84,
// ~100 MB phantom HBM traffic, MfmaUtil 7.5%) — rule-#20 failure mode.
// Fix: eight NAMED i32x8 SSA values, hand-unrolled 16-MFMA block, and
// `#pragma unroll 1` on the c-loop so hoisted loads can't pressure-spill.
__device__ __forceinline__ i32x8 load_frag(const uint8_t* p) {
    const int2 w0 = *(const int2*)(p);
    const int2 w1 = *(const int2*)(p + 1024);
    const int2 w2 = *(const int2*)(p + 2048);
    const int2 w3 = *(const int2*)(p + 3072);
    i32x8 v;
    v[0] = w0.x; v[1] = w0.y;
    v[2] = w1.x; v[3] = w1.y;
    v[4] = w2.x; v[5] = w2.y;
    v[6] = w3.x; v[7] = w3.y;
    return v;
}

#define MFMA128(A, B, C) __builtin_amdgcn_mfma_scale_f32_16x16x128_f8f6f4( \
    (A), (B), (C), 0, 0, 0, 0x7F7F7F7Fu, 0, 0x7F7F7F7Fu)

__global__ __launch_bounds__(256, 3)
void cc_gemm(const uint8_t* __restrict__ Fn2, const int* __restrict__ cl,
             float* __restrict__ Pt, float* __restrict__ Pp) {
    __shared__ int crow[TILE], ccol[TILE];
    __shared__ float2 rsum[2][TILE];
    __shared__ float2 csum[2][TILE];

    const int tid  = threadIdx.x;
    const int wave = tid >> 6;
    const int lane = tid & 63;

    int rem = blockIdx.x, bm = 0;
    while (rem >= NTB - bm) { rem -= NTB - bm; ++bm; }
    const int bn = bm + rem;
    const bool diag = (bm == bn);

    if (tid < TILE)            crow[tid]        = cl[bm * TILE + tid];
    else                       ccol[tid - TILE] = cl[bn * TILE + (tid - TILE)];

    const int wr = wave >> 1, wc = wave & 1;    // 2x2 wave grid, 64x64 each
    const int q   = lane >> 4;
    const int n15 = lane & 15;

    f32x4 acc[4][4];
    #pragma unroll
    for (int t = 0; t < 4; ++t)
        #pragma unroll
        for (int u = 0; u < 4; ++u) acc[t][u] = (f32x4)(0.0f);

    // K=128 operand: lane (q,n15) holds row/col n15, k = q*32 + p*8 + byte.
    // In Fn2 layout: kc = 2c+(q>>1), ks = q&1, sub-block p at stride 1024.
    const int koff = (q >> 1) * 8192 + (q & 1) * 4096 + n15 * 8;
    const uint8_t* Ag = Fn2 + (size_t)bm * PANEL_BYTES + koff + (wr * 64) * 8;
    const uint8_t* Bg = Fn2 + (size_t)bn * PANEL_BYTES + koff + (wc * 64) * 8;

    #pragma unroll 1
    for (int c = 0; c < D / 128; ++c) {
        const uint8_t* pa = Ag + c * 16384;
        const uint8_t* pb = Bg + c * 16384;
        const i32x8 a0 = load_frag(pa);
        const i32x8 a1 = load_frag(pa + 128);
        const i32x8 a2 = load_frag(pa + 256);
        const i32x8 a3 = load_frag(pa + 384);
        const i32x8 b0 = load_frag(pb);
        const i32x8 b1 = load_frag(pb + 128);
        const i32x8 b2 = load_frag(pb + 256);
        const i32x8 b3 = load_frag(pb + 384);
        acc[0][0] = MFMA128(a0, b0, acc[0][0]);
        acc[0][1] = MFMA128(a0, b1, acc[0][1]);
        acc[0][2] = MFMA128(a0, b2, acc[0][2]);
        acc[0][3] = MFMA128(a0, b3, acc[0][3]);
        acc[1][0] = MFMA128(a1, b0, acc[1][0]);
        acc[1][1] = MFMA128(a1, b1, acc[1][1]);
        acc[1][2] = MFMA128(a1, b2, acc[1][2]);
        acc[1][3] = MFMA128(a1, b3, acc[1][3]);
        acc[2][0] = MFMA128(a2, b0, acc[2][0]);
        acc[2][1] = MFMA128(a2, b1, acc[2][1]);
        acc[2][2] = MFMA128(a2, b2, acc[2][2]);
        acc[2][3] = MFMA128(a2, b3, acc[2][3]);
        acc[3][0] = MFMA128(a3, b0, acc[3][0]);
        acc[3][1] = MFMA128(a3, b1, acc[3][1]);
        acc[3][2] = MFMA128(a3, b2, acc[3][2]);
        acc[3][3] = MFMA128(a3, b3, acc[3][3]);
    }

    __syncthreads();   // crow/ccol visible to all waves for the epilogue

    // epilogue: sim = dot/256; e = exp2(dot * 10*log2(e)/256)
    // C layout col=lane&15, row=q*4+reg (shape-determined, same as 16x16x32)
    const float SC = 0.05635527503472514f;
    int cc[4];
    #pragma unroll
    for (int u = 0; u < 4; ++u) cc[u] = ccol[wc * 64 + u * 16 + n15];

    float ra[16], rp[16];            // per-lane row partials, idx = t*4+r
    float ce[4] = {0.f, 0.f, 0.f, 0.f};
    float cp2[4] = {0.f, 0.f, 0.f, 0.f};

    #pragma unroll
    for (int t = 0; t < 4; ++t) {
        #pragma unroll
        for (int r = 0; r < 4; ++r) {
            const int myc = crow[wr * 64 + t * 16 + q * 4 + r];
            float te = 0.0f, tp = 0.0f;
            #pragma unroll
            for (int u = 0; u < 4; ++u) {
                const float e  = exp2f(acc[t][u][r] * SC);
                const float ep = (cc[u] == myc) ? e : 0.0f;
                te += e;  tp += ep;
                ce[u] += e;  cp2[u] += ep;
            }
            ra[t * 4 + r] = te;  rp[t * 4 + r] = tp;
        }
    }

    // tree-packed reduction (R13-verified): 16 row sums over 16 lanes,
    // 15 shuffles/array. After stage m the kept index gains `half` iff lane&m.
    {
        int len = 16;
        #pragma unroll
        for (int m = 1; m <= 8; m <<= 1) {
            const int half = len >> 1;
            const bool hiL = (lane & m) != 0;
            #pragma unroll
            for (int j = 0; j < half; ++j) {
                float sa = hiL ? ra[j] : ra[j + half];
                float sp = hiL ? rp[j] : rp[j + half];
                sa = __shfl_xor(sa, m, 64);
                sp = __shfl_xor(sp, m, 64);
                ra[j] = (hiL ? ra[j + half] : ra[j]) + sa;
                rp[j] = (hiL ? rp[j + half] : rp[j]) + sp;
            }
            len = half;
        }
        const int idx = ((n15 & 1) << 3) | ((n15 & 2) << 1) | ((n15 & 4) >> 1) | ((n15 & 8) >> 3);
        const int row = wr * 64 + (idx >> 2) * 16 + q * 4 + (idx & 3);
        rsum[wc][row] = make_float2(ra[0], rp[0]);
    }

    // column sums: 4 values over the 4 q-groups (masks 16, 32), 3 shuffles/array
    if (!diag) {
        int len = 4;
        #pragma unroll
        for (int m = 16; m <= 32; m <<= 1) {
            const int half = len >> 1;
            const bool hiL = (lane & m) != 0;
            #pragma unroll
            for (int j = 0; j < half; ++j) {
                float se = hiL ? ce[j] : ce[j + half];
                float sp = hiL ? cp2[j] : cp2[j + half];
                se = __shfl_xor(se, m, 64);
                sp = __shfl_xor(sp, m, 64);
                ce[j] = (hiL ? ce[j + half] : ce[j]) + se;
                cp2[j] = (hiL ? cp2[j + half] : cp2[j]) + sp;
            }
            len = half;
        }
        const int u = (((lane >> 4) & 1) << 1) | ((lane >> 5) & 1);
        const int col = wc * 64 + u * 16 + n15;
        csum[wr][col] = make_float2(ce[0], cp2[0]);
    }

    __syncthreads();
    if (tid < TILE) {
        const float2 r0 = rsum[0][tid], r1 = rsum[1][tid];
        const size_t o = (size_t)bn * N + bm * TILE + tid;
        Pt[o] = r0.x + r1.x;  Pp[o] = r0.y + r1.y;
    } else if (!diag) {
        const int c = tid - TILE;
        const float2 c0 = csum[0][c], c1 = csum[1][c];
        const size_t o = (size_t)bm * N + bn * TILE + c;
        Pt[o] = c0.x + c1.x;  Pp[o] = c0.y + c1.y;
    }
}

// 32 blocks x 256: row i sums its 64 slices, loss, block-reduce, atomicAdd out
__global__ void cc_finalize(const float* __restrict__ Pt, const float* __restrict__ Pp,
                            float* __restrict__ out) {
    __shared__ float red[4];
    const int i = blockIdx.x * 256 + threadIdx.x;
    float tv = 0.0f, pv = 0.0f;
    #pragma unroll 8
    for (int s = 0; s < NTB; ++s) {
        tv += Pt[(size_t)s * N + i];
        pv += Pp[(size_t)s * N + i];
    }
    float l = __logf(tv + 1e-8f) - __logf(pv);
    #pragma unroll
    for (int m = 32; m; m >>= 1) l += __shfl_xor(l, m, 64);
    const int wv = threadIdx.x >> 6, lane = threadIdx.x & 63;
    if (lane == 0) red[wv] = l;
    __syncthreads();
    if (threadIdx.x == 0) atomicAdd(out, red[0] + red[1] + red[2] + red[3]);
}

extern "C" void kernel_launch(void* const* d_in, const int* in_sizes, int n_in,
                              void* d_out, int out_size, void* d_ws, size_t ws_size,
                              hipStream_t stream) {
    const float* F  = (const float*)d_in[0];
    const int*   cl = (const int*)d_in[1];
    float* out = (float*)d_out;

    uint8_t* Fn2 = (uint8_t*)d_ws;                               // 4 MB fp8 swizzled
    float* Pt  = (float*)((char*)d_ws + (size_t)N * D);          // 2 MB
    float* Pp  = Pt + (size_t)NTB * N;                           // 2 MB

    cc_normalize<<<N / 4, 256, 0, stream>>>(F, Fn2, out);
    cc_gemm<<<NBLK, 256, 0, stream>>>(Fn2, cl, Pt, Pp);
    cc_finalize<<<N / 256, 256, 0, stream>>>(Pt, Pp, out);
}